// Round 2
// baseline (337.017 us; speedup 1.0000x reference)
//
#include <hip/hip_runtime.h>

#define NB 22
#define NFR_B 7499
#define BATCH 32
#define ROWLEN 960000
#define NFTOT (BATCH * NFR_B)

__constant__ int c_bands[NB] = {0,4,8,12,16,20,24,28,32,40,44,48,52,56,64,72,80,88,96,104,112,128};

// DPP / swizzle lane exchanges (VALU / LDS-pipe but conflict-free)
#define XDPP(x, CTRL) __int_as_float(__builtin_amdgcn_update_dpp(0, __float_as_int(x), CTRL, 0xF, 0xF, true))
#define XSWZ(x, PATT) __int_as_float(__builtin_amdgcn_ds_swizzle(__float_as_int(x), PATT))
#define E0(x) XDPP(x, 0xB1)      // xor 1  (quad_perm [1,0,3,2])
#define E1(x) XDPP(x, 0x4E)      // xor 2  (quad_perm [2,3,0,1])
#define E2(x) XSWZ(x, 0x101F)    // xor 4  (ds_swizzle xor-mode)
#define E3(x) XDPP(x, 0x128)     // xor 8  (row_ror:8, 8 == -8 mod 16)
#define E4(x) XSWZ(x, 0x401F)    // xor 16
#define E5(x) __shfl_xor(x, 32, 64)

// butterfly with sign folded into per-lane twiddle: res = u + W_s * v
#define STAGE(S, EXR)                                                   \
  { const bool up = ((lane >> S) & 1) != 0;                             \
    const float Wr = twr[S], Wi = twi[S];                               \
    const float ear = EXR(ar), eai = EXR(ai);                           \
    const float ebr = EXR(br), ebi = EXR(bi);                           \
    const float u0r = up ? ear : ar, u0i = up ? eai : ai;               \
    const float v0r = up ? ar : ear, v0i = up ? ai : eai;               \
    ar = u0r + (Wr * v0r - Wi * v0i);                                   \
    ai = u0i + (Wr * v0i + Wi * v0r);                                   \
    const float u1r = up ? ebr : br, u1i = up ? ebi : bi;               \
    const float v1r = up ? br : ebr, v1i = up ? bi : ebi;               \
    br = u1r + (Wr * v1r - Wi * v1i);                                   \
    bi = u1i + (Wr * v1i + Wi * v1r); }

__global__ __launch_bounds__(256, 8)
void feat_kernel(const float* __restrict__ x, float* __restrict__ out) {
    const int lane = threadIdx.x & 63;
    const int wid  = threadIdx.x >> 6;
    const int gwave  = blockIdx.x * (blockDim.x >> 6) + wid;
    const int nwaves = gridDim.x * (blockDim.x >> 6);

    const float PI = 3.14159265358979323846f;

    // 7-bit bit-reversal of lane (bit6 = 0 -> r is even)
    const int r = (int)(__brev((unsigned)lane) >> 25);

    // window for the 4 loaded samples
    float winv[4];
    #pragma unroll
    for (int j = 0; j < 4; ++j) winv[j] = sinf(PI * (float)(2 * r + j) / 256.0f);

    // per-stage SIGNED twiddles (sign of the butterfly folded in)
    float twr[6], twi[6];
    #pragma unroll
    for (int s = 0; s < 6; ++s) {
        const int m = 1 << s;
        const float ang = -PI * (float)(lane & (m - 1)) / (float)m;
        float cw = cosf(ang), sw = sinf(ang);
        const bool bit = ((lane >> s) & 1) != 0;
        twr[s] = bit ? -cw : cw;
        twi[s] = bit ? -sw : sw;
    }
    const float w6r = cosf(-PI * (float)lane / 64.0f);
    const float w6i = sinf(-PI * (float)lane / 64.0f);
    const float c1 = cosf(PI * (float)lane / 128.0f);
    const float s1 = sinf(PI * (float)lane / 128.0f);

    // ---- band segmentation constants ----
    // pw1 = bin `lane` (0..63): segment seg1 in 0..13
    int seg1 = 0;
    for (int j = 1; j < 14; ++j) if (lane >= c_bands[j]) seg1 = j;
    const int wid1 = c_bands[seg1 + 1] - c_bands[seg1];
    const float a1 = (float)(lane - c_bands[seg1]) / (float)wid1;
    const bool is8_1 = (wid1 == 8);
    // pw2 = bin lane+64: segment seg2 in 14..20
    const int bin2 = lane + 64;
    int seg2 = 14;
    for (int j = 15; j < 21; ++j) if (bin2 >= c_bands[j]) seg2 = j;
    const int wid2 = c_bands[seg2 + 1] - c_bands[seg2];
    const float a2 = (float)(bin2 - c_bands[seg2]) / (float)wid2;
    const bool is16_2 = (seg2 == 20);

    // gather indices: lane c needs A(seg c-1) and D(seg c)
    const int c = lane;
    int idxA = 0; bool selA1 = true;
    if (c >= 1 && c <= 21) {
        if (c - 1 <= 13) { idxA = c_bands[c - 1]; selA1 = true; }
        else             { idxA = c_bands[c - 1] - 64; selA1 = false; }
    }
    int idxD = 0; bool selD1 = true;
    if (c <= 20) {
        if (c <= 13) { idxD = c_bands[c]; selD1 = true; }
        else         { idxD = c_bands[c] - 64; selD1 = false; }
    }

    // contiguous frame chunk per wave
    const int chunk = (NFTOT + nwaves - 1) / nwaves;
    int f0 = gwave * chunk;
    int f1 = f0 + chunk; if (f1 > NFTOT) f1 = NFTOT;
    if (f0 >= f1) return;

    int bb = f0 / NFR_B;
    int t  = f0 - bb * NFR_B;
    const float* xp = x + (size_t)bb * ROWLEN + (size_t)t * 128;
    float* outp = out + (size_t)f0 * NB;

    for (int f = f0; f < f1; ++f) {
        const float4 v = *(const float4*)(xp + 2 * r);
        float ar = v.x * winv[0], ai = v.y * winv[1];
        float br = v.z * winv[2], bi = v.w * winv[3];

        STAGE(0, E0)
        STAGE(1, E1)
        STAGE(2, E2)
        STAGE(3, E3)
        STAGE(4, E4)
        STAGE(5, E5)

        // span-64 stage (lane-local)
        {
            const float tr = w6r * br - w6i * bi, ti = w6r * bi + w6i * br;
            const float nar = ar + tr, nai = ai + ti;
            br = ar - tr; bi = ai - ti;
            ar = nar; ai = nai;
        }
        // Hermitian unpack: a = Z[lane], b = Z[lane+64] -> pw[lane], pw[lane+64]
        const int pidx = (64 - lane) & 63;
        const float par = __shfl(ar, pidx, 64), pai = __shfl(ai, pidx, 64);
        const float pbr = __shfl(br, pidx, 64), pbi = __shfl(bi, pidx, 64);
        const float P1r = (lane == 0) ? par : pbr, P1i = (lane == 0) ? pai : pbi;
        const float P2r = (lane == 0) ? pbr : par, P2i = (lane == 0) ? pbi : pai;

        float Er = 0.5f * (ar + P1r), Ei = 0.5f * (ai - P1i);
        float Or_ = 0.5f * (ar - P1r), Oi = 0.5f * (ai + P1i);
        const float X1r = Er + c1 * Oi - s1 * Or_;
        const float X1i = Ei - c1 * Or_ - s1 * Oi;
        const float pw1 = X1r * X1r + X1i * X1i;

        Er = 0.5f * (br + P2r); Ei = 0.5f * (bi - P2i);
        Or_ = 0.5f * (br - P2r); Oi = 0.5f * (bi + P2i);
        const float X2r = Er - s1 * Oi - c1 * Or_;
        const float X2i = Ei + s1 * Or_ - c1 * Oi;
        const float pw2 = X2r * X2r + X2i * X2i;

        // ---- segmented band reduction (all lanes) ----
        // pw1: segments 4- or 8-wide, 4/8-aligned
        float S1 = pw1, T1 = a1 * pw1;
        { float e = E0(S1); S1 += e; e = E0(T1); T1 += e; }
        { float e = E1(S1); S1 += e; e = E1(T1); T1 += e; }
        { float e4s = E2(S1), e4t = E2(T1);
          S1 += is8_1 ? e4s : 0.0f; T1 += is8_1 ? e4t : 0.0f; }
        const float D1 = S1 - T1;
        // pw2: segments 8-wide (8-aligned) except last 16-wide (row-aligned)
        float S2 = pw2, T2 = a2 * pw2;
        { float e = E0(S2); S2 += e; e = E0(T2); T2 += e; }
        { float e = E1(S2); S2 += e; e = E1(T2); T2 += e; }
        { float e = E2(S2); S2 += e; e = E2(T2); T2 += e; }
        { float e8s = E3(S2), e8t = E3(T2);
          S2 += is16_2 ? e8s : 0.0f; T2 += is16_2 ? e8t : 0.0f; }
        const float D2 = S2 - T2;

        // gather per-band pieces: band c = A(seg c-1) + D(seg c), edges x2
        const float gA1 = __shfl(T1, idxA, 64), gA2 = __shfl(T2, idxA, 64);
        const float gD1 = __shfl(D1, idxD, 64), gD2 = __shfl(D2, idxD, 64);
        const float A_prev = selA1 ? gA1 : gA2;
        const float D_cur  = selD1 ? gD1 : gD2;
        float band = A_prev + D_cur;
        if (c == 0)  band = 2.0f * D_cur;
        if (c == 21) band = 2.0f * A_prev;

        if (c < NB) outp[c] = 0.30102999566398120f * __log2f(band);

        // advance
        xp += 128;
        outp += NB;
        if (++t == NFR_B) { t = 0; xp += 128; }
    }
}

// second pass: in-place 22x22 DCT on d_out rows
__global__ __launch_bounds__(256, 8)
void dct_kernel(float* __restrict__ io) {
    __shared__ float dctL[NB * NB];
    const float PI = 3.14159265358979323846f;
    for (int i = threadIdx.x; i < NB * NB; i += 256) {
        const int cc = i / NB, b = i - cc * NB;
        const float norm = sqrtf(2.0f / (float)NB) * ((cc == 0) ? 0.70710678118654752f : 1.0f);
        dctL[i] = norm * cosf(PI / (float)NB * ((float)b + 0.5f) * (float)cc);
    }
    __syncthreads();
    const int tid = blockIdx.x * blockDim.x + threadIdx.x;
    const int stride = gridDim.x * blockDim.x;
    for (int f = tid; f < NFTOT; f += stride) {
        float* row = io + (size_t)f * NB;
        float rv[NB];
        #pragma unroll
        for (int j = 0; j < 11; ++j) {
            const float2 v = *(const float2*)(row + 2 * j);
            rv[2 * j] = v.x; rv[2 * j + 1] = v.y;
        }
        #pragma unroll
        for (int cc = 0; cc < NB; cc += 2) {
            float acc0 = 0.0f, acc1 = 0.0f;
            #pragma unroll
            for (int b = 0; b < NB; ++b) {
                acc0 += dctL[cc * NB + b] * rv[b];
                acc1 += dctL[(cc + 1) * NB + b] * rv[b];
            }
            *(float2*)(row + cc) = make_float2(acc0, acc1);
        }
    }
}

extern "C" void kernel_launch(void* const* d_in, const int* in_sizes, int n_in,
                              void* d_out, int out_size, void* d_ws, size_t ws_size,
                              hipStream_t stream) {
    const float* x = (const float*)d_in[0];
    float* out = (float*)d_out;
    feat_kernel<<<2048, 256, 0, stream>>>(x, out);
    dct_kernel<<<1024, 256, 0, stream>>>(out);
}

// Round 3
// 132.426 us; speedup vs baseline: 2.5450x; 2.5450x over previous
//
#include <hip/hip_runtime.h>

#define NB 22
#define NFR_B 7499
#define BATCH 32
#define ROWLEN 960000
#define NFTOT (BATCH * NFR_B)

__constant__ int c_bands[NB] = {0,4,8,12,16,20,24,28,32,40,44,48,52,56,64,72,80,88,96,104,112,128};

// DPP / swizzle lane exchanges (VALU / LDS-pipe but conflict-free)
#define XDPP(x, CTRL) __int_as_float(__builtin_amdgcn_update_dpp(0, __float_as_int(x), CTRL, 0xF, 0xF, true))
#define XSWZ(x, PATT) __int_as_float(__builtin_amdgcn_ds_swizzle(__float_as_int(x), PATT))
#define E0(x) XDPP(x, 0xB1)      // xor 1  (quad_perm [1,0,3,2])
#define E1(x) XDPP(x, 0x4E)      // xor 2  (quad_perm [2,3,0,1])
#define E2(x) XSWZ(x, 0x101F)    // xor 4  (ds_swizzle xor-mode)
#define E3(x) XDPP(x, 0x128)     // xor 8  (row_ror:8)
#define E4(x) XSWZ(x, 0x401F)    // xor 16
#define E5(x) __shfl_xor(x, 32, 64)

// butterfly with sign folded into per-lane twiddle: res = u + W_s * v
#define STAGE(S, EXR)                                                   \
  { const bool up = ((lane >> S) & 1) != 0;                             \
    const float Wr = twr[S], Wi = twi[S];                               \
    const float ear = EXR(ar), eai = EXR(ai);                           \
    const float ebr = EXR(br), ebi = EXR(bi);                           \
    const float u0r = up ? ear : ar, u0i = up ? eai : ai;               \
    const float v0r = up ? ar : ear, v0i = up ? ai : eai;               \
    ar = u0r + (Wr * v0r - Wi * v0i);                                   \
    ai = u0i + (Wr * v0i + Wi * v0r);                                   \
    const float u1r = up ? ebr : br, u1i = up ? ebi : bi;               \
    const float v1r = up ? br : ebr, v1i = up ? bi : ebi;               \
    br = u1r + (Wr * v1r - Wi * v1i);                                   \
    bi = u1i + (Wr * v1i + Wi * v1r); }

__global__ __launch_bounds__(256, 4)
void feat_kernel(const float* __restrict__ x, float* __restrict__ out) {
    const int lane = threadIdx.x & 63;
    const int wid  = threadIdx.x >> 6;
    const int gwave  = blockIdx.x * (blockDim.x >> 6) + wid;
    const int nwaves = gridDim.x * (blockDim.x >> 6);

    const float PI = 3.14159265358979323846f;

    // 7-bit bit-reversal of lane (bit6 = 0 -> r is even)
    const int r = (int)(__brev((unsigned)lane) >> 25);

    // window for the 4 loaded samples
    float winv[4];
    #pragma unroll
    for (int j = 0; j < 4; ++j) winv[j] = sinf(PI * (float)(2 * r + j) / 256.0f);

    // per-stage SIGNED twiddles (sign of the butterfly folded in)
    float twr[6], twi[6];
    #pragma unroll
    for (int s = 0; s < 6; ++s) {
        const int m = 1 << s;
        const float ang = -PI * (float)(lane & (m - 1)) / (float)m;
        float cw = cosf(ang), sw = sinf(ang);
        const bool bit = ((lane >> s) & 1) != 0;
        twr[s] = bit ? -cw : cw;
        twi[s] = bit ? -sw : sw;
    }
    const float w6r = cosf(-PI * (float)lane / 64.0f);
    const float w6i = sinf(-PI * (float)lane / 64.0f);
    const float c1 = cosf(PI * (float)lane / 128.0f);
    const float s1 = sinf(PI * (float)lane / 128.0f);

    // ---- band segmentation constants ----
    int seg1 = 0;
    for (int j = 1; j < 14; ++j) if (lane >= c_bands[j]) seg1 = j;
    const int wid1 = c_bands[seg1 + 1] - c_bands[seg1];
    const float a1 = (float)(lane - c_bands[seg1]) / (float)wid1;
    const bool is8_1 = (wid1 == 8);
    const int bin2 = lane + 64;
    int seg2 = 14;
    for (int j = 15; j < 21; ++j) if (bin2 >= c_bands[j]) seg2 = j;
    const int wid2 = c_bands[seg2 + 1] - c_bands[seg2];
    const float a2 = (float)(bin2 - c_bands[seg2]) / (float)wid2;
    const bool is16_2 = (seg2 == 20);

    // gather indices: lane c needs A(seg c-1) and D(seg c)
    const int c = lane;
    int idxA = 0; bool selA1 = true;
    if (c >= 1 && c <= 21) {
        if (c - 1 <= 13) { idxA = c_bands[c - 1]; selA1 = true; }
        else             { idxA = c_bands[c - 1] - 64; selA1 = false; }
    }
    int idxD = 0; bool selD1 = true;
    if (c <= 20) {
        if (c <= 13) { idxD = c_bands[c]; selD1 = true; }
        else         { idxD = c_bands[c] - 64; selD1 = false; }
    }

    // DCT-II row for output index c: feat[c] = sum_b coef[b] * lg[b]
    float coef[NB];
    {
        const float norm = sqrtf(2.0f / (float)NB) * ((c == 0) ? 0.70710678118654752f : 1.0f);
        #pragma unroll
        for (int b = 0; b < NB; ++b)
            coef[b] = norm * cosf(PI / (float)NB * ((float)b + 0.5f) * (float)c);
    }

    // contiguous frame chunk per wave
    const int chunk = (NFTOT + nwaves - 1) / nwaves;
    int f0 = gwave * chunk;
    int f1 = f0 + chunk; if (f1 > NFTOT) f1 = NFTOT;
    if (f0 >= f1) return;

    int bb = f0 / NFR_B;
    int t  = f0 - bb * NFR_B;
    const float* xp = x + (size_t)bb * ROWLEN + (size_t)t * 128;
    float* outp = out + (size_t)f0 * NB;

    float4 v = *(const float4*)(xp + 2 * r);   // prefetched current frame

    for (int f = f0; f < f1; ++f) {
        // prefetch next frame's data (hides HBM/L2 latency under ~300 VALU ops)
        int tn = t + 1;
        const float* xpn = xp + 128;
        if (tn == NFR_B) { tn = 0; xpn += 128; }
        float4 vn = v;
        if (f + 1 < f1) vn = *(const float4*)(xpn + 2 * r);

        float ar = v.x * winv[0], ai = v.y * winv[1];
        float br = v.z * winv[2], bi = v.w * winv[3];

        STAGE(0, E0)
        STAGE(1, E1)
        STAGE(2, E2)
        STAGE(3, E3)
        STAGE(4, E4)
        STAGE(5, E5)

        // span-64 stage (lane-local)
        {
            const float tr = w6r * br - w6i * bi, ti = w6r * bi + w6i * br;
            const float nar = ar + tr, nai = ai + ti;
            br = ar - tr; bi = ai - ti;
            ar = nar; ai = nai;
        }
        // Hermitian unpack: a = Z[lane], b = Z[lane+64] -> pw[lane], pw[lane+64]
        const int pidx = (64 - lane) & 63;
        const float par = __shfl(ar, pidx, 64), pai = __shfl(ai, pidx, 64);
        const float pbr = __shfl(br, pidx, 64), pbi = __shfl(bi, pidx, 64);
        const float P1r = (lane == 0) ? par : pbr, P1i = (lane == 0) ? pai : pbi;
        const float P2r = (lane == 0) ? pbr : par, P2i = (lane == 0) ? pbi : pai;

        float Er = 0.5f * (ar + P1r), Ei = 0.5f * (ai - P1i);
        float Or_ = 0.5f * (ar - P1r), Oi = 0.5f * (ai + P1i);
        const float X1r = Er + c1 * Oi - s1 * Or_;
        const float X1i = Ei - c1 * Or_ - s1 * Oi;
        const float pw1 = X1r * X1r + X1i * X1i;

        Er = 0.5f * (br + P2r); Ei = 0.5f * (bi - P2i);
        Or_ = 0.5f * (br - P2r); Oi = 0.5f * (bi + P2i);
        const float X2r = Er - s1 * Oi - c1 * Or_;
        const float X2i = Ei + s1 * Or_ - c1 * Oi;
        const float pw2 = X2r * X2r + X2i * X2i;

        // ---- segmented band reduction (all lanes) ----
        float S1 = pw1, T1 = a1 * pw1;
        { float e = E0(S1); S1 += e; e = E0(T1); T1 += e; }
        { float e = E1(S1); S1 += e; e = E1(T1); T1 += e; }
        { float e4s = E2(S1), e4t = E2(T1);
          S1 += is8_1 ? e4s : 0.0f; T1 += is8_1 ? e4t : 0.0f; }
        const float D1 = S1 - T1;
        float S2 = pw2, T2 = a2 * pw2;
        { float e = E0(S2); S2 += e; e = E0(T2); T2 += e; }
        { float e = E1(S2); S2 += e; e = E1(T2); T2 += e; }
        { float e = E2(S2); S2 += e; e = E2(T2); T2 += e; }
        { float e8s = E3(S2), e8t = E3(T2);
          S2 += is16_2 ? e8s : 0.0f; T2 += is16_2 ? e8t : 0.0f; }
        const float D2 = S2 - T2;

        // gather per-band pieces: band c = A(seg c-1) + D(seg c), edges x2
        const float gA1 = __shfl(T1, idxA, 64), gA2 = __shfl(T2, idxA, 64);
        const float gD1 = __shfl(D1, idxD, 64), gD2 = __shfl(D2, idxD, 64);
        const float A_prev = selA1 ? gA1 : gA2;
        const float D_cur  = selD1 ? gD1 : gD2;
        float band = A_prev + D_cur;
        if (c == 0)  band = 2.0f * D_cur;
        if (c == 21) band = 2.0f * A_prev;

        const float lg = 0.30102999566398120f * __log2f(band);

        // ---- in-register 22-pt DCT: broadcast lg[b] from lane b ----
        float acc = 0.0f;
        #pragma unroll
        for (int b = 0; b < NB; ++b) {
            const float lgb = __shfl(lg, b, 64);   // compile-time lane -> readlane
            acc = fmaf(coef[b], lgb, acc);
        }

        if (c < NB) outp[c] = acc;

        // advance
        v = vn; t = tn; xp = xpn;
        outp += NB;
    }
}

extern "C" void kernel_launch(void* const* d_in, const int* in_sizes, int n_in,
                              void* d_out, int out_size, void* d_ws, size_t ws_size,
                              hipStream_t stream) {
    const float* x = (const float*)d_in[0];
    float* out = (float*)d_out;
    feat_kernel<<<2048, 256, 0, stream>>>(x, out);
}

// Round 4
// 102.110 us; speedup vs baseline: 3.3005x; 1.2969x over previous
//
#include <hip/hip_runtime.h>

#define NB 22
#define NFR_B 7499
#define BATCH 32
#define ROWLEN 960000
#define NFTOT (BATCH * NFR_B)

typedef float f2 __attribute__((ext_vector_type(2)));

__constant__ int c_bands[NB] = {0,4,8,12,16,20,24,28,32,40,44,48,52,56,64,72,80,88,96,104,112,128};

// 32-bit lane exchanges
#define XDPP(x, CTRL) __int_as_float(__builtin_amdgcn_update_dpp(0, __float_as_int(x), CTRL, 0xF, 0xF, true))
#define XSWZ(x, PATT) __int_as_float(__builtin_amdgcn_ds_swizzle(__float_as_int(x), PATT))
#define E0S(x) XDPP(x, 0xB1)      // xor 1
#define E1S(x) XDPP(x, 0x4E)      // xor 2
#define E2S(x) XSWZ(x, 0x101F)    // xor 4
#define E3S(x) XDPP(x, 0x128)     // xor 8 (row_ror:8)
#define E4S(x) XSWZ(x, 0x401F)    // xor 16
#define E5S(x) __shfl_xor(x, 32, 64)

__device__ __forceinline__ f2 mk2(float v) { f2 r; r.x = v; r.y = v; return r; }
__device__ __forceinline__ f2 ex0v(f2 v) { f2 r; r.x = E0S(v.x); r.y = E0S(v.y); return r; }
__device__ __forceinline__ f2 ex1v(f2 v) { f2 r; r.x = E1S(v.x); r.y = E1S(v.y); return r; }
__device__ __forceinline__ f2 ex2v(f2 v) { f2 r; r.x = E2S(v.x); r.y = E2S(v.y); return r; }
__device__ __forceinline__ f2 ex3v(f2 v) { f2 r; r.x = E3S(v.x); r.y = E3S(v.y); return r; }
__device__ __forceinline__ f2 ex4v(f2 v) { f2 r; r.x = E4S(v.x); r.y = E4S(v.y); return r; }
__device__ __forceinline__ f2 ex5v(f2 v) { f2 r; r.x = E5S(v.x); r.y = E5S(v.y); return r; }
__device__ __forceinline__ f2 shflv(f2 v, int idx) {
    f2 r; r.x = __shfl(v.x, idx, 64); r.y = __shfl(v.y, idx, 64); return r;
}

// general packed stage: res = W1*x + W2*e (select-free butterfly)
#define PSTAGE(S, EXF)                                                    \
  { const f2 exr_a = EXF(ar2), exi_a = EXF(ai2);                          \
    const f2 exr_b = EXF(br2), exi_b = EXF(bi2);                          \
    const f2 w1r = W1r[S], w1i = W1i[S], w2r = W2r[S], w2i = W2i[S];      \
    const f2 nar = w1r*ar2 - w1i*ai2 + w2r*exr_a - w2i*exi_a;             \
    const f2 nai = w1r*ai2 + w1i*ar2 + w2r*exi_a + w2i*exr_a;             \
    const f2 nbr = w1r*br2 - w1i*bi2 + w2r*exr_b - w2i*exi_b;             \
    const f2 nbi = w1r*bi2 + w1i*br2 + w2r*exi_b + w2i*exr_b;             \
    ar2 = nar; ai2 = nai; br2 = nbr; bi2 = nbi; }

__global__ __launch_bounds__(256, 3)
void feat_kernel(const float* __restrict__ x, float* __restrict__ out) {
    const int lane = threadIdx.x & 63;
    const int wid  = threadIdx.x >> 6;
    const int gwave  = blockIdx.x * (blockDim.x >> 6) + wid;
    const int nwaves = gridDim.x * (blockDim.x >> 6);

    const float PI = 3.14159265358979323846f;

    // 7-bit bit-reversal of lane (bit6 = 0 -> r even)
    const int r = (int)(__brev((unsigned)lane) >> 25);

    float winv[4];
    #pragma unroll
    for (int j = 0; j < 4; ++j) winv[j] = sinf(PI * (float)(2 * r + j) / 256.0f);

    // select-free butterfly constants: W1 = up ? -w : 1, W2 = up ? 1 : w
    f2 W1r[6], W1i[6], W2r[6], W2i[6];
    #pragma unroll
    for (int s = 1; s < 6; ++s) {
        const int m = 1 << s;
        const float ang = -PI * (float)(lane & (m - 1)) / (float)m;
        const float wr = cosf(ang), wi = sinf(ang);
        const bool up = ((lane >> s) & 1) != 0;
        W1r[s] = mk2(up ? -wr : 1.0f);
        W1i[s] = mk2(up ? -wi : 0.0f);
        W2r[s] = mk2(up ? 1.0f : wr);
        W2i[s] = mk2(up ? 0.0f : wi);
    }
    const f2 sgn2 = mk2((lane & 1) ? -1.0f : 1.0f);   // stage 0 (w = 1)
    const f2 w6r2 = mk2(cosf(-PI * (float)lane / 64.0f));
    const f2 w6i2 = mk2(sinf(-PI * (float)lane / 64.0f));
    const f2 c1_2 = mk2(cosf(PI * (float)lane / 128.0f));
    const f2 s1_2 = mk2(sinf(PI * (float)lane / 128.0f));

    // ---- band segmentation constants ----
    int seg1 = 0;
    for (int j = 1; j < 14; ++j) if (lane >= c_bands[j]) seg1 = j;
    const int wd1 = c_bands[seg1 + 1] - c_bands[seg1];
    const f2 a1_2 = mk2((float)(lane - c_bands[seg1]) / (float)wd1);
    const f2 m8_2 = mk2((wd1 == 8) ? 1.0f : 0.0f);
    const int bin2 = lane + 64;
    int seg2 = 14;
    for (int j = 15; j < 21; ++j) if (bin2 >= c_bands[j]) seg2 = j;
    const int wd2 = c_bands[seg2 + 1] - c_bands[seg2];
    const f2 a2_2 = mk2((float)(bin2 - c_bands[seg2]) / (float)wd2);
    const f2 m16_2 = mk2((seg2 == 20) ? 1.0f : 0.0f);

    // gather indices: lane c needs A(seg c-1) and D(seg c)
    const int c = lane;
    int idxA = 0; bool selA1 = true;
    if (c >= 1 && c <= 21) {
        if (c - 1 <= 13) { idxA = c_bands[c - 1]; selA1 = true; }
        else             { idxA = c_bands[c - 1] - 64; selA1 = false; }
    }
    int idxD = 0; bool selD1 = true;
    if (c <= 20) {
        if (c <= 13) { idxD = c_bands[c]; selD1 = true; }
        else         { idxD = c_bands[c] - 64; selD1 = false; }
    }

    // DCT row for half-lane index oc; 0.30103 (log10(2)) folded into coef
    const int oc = lane & 31;
    float coef[NB];
    {
        const float norm = 0.30102999566398120f * sqrtf(2.0f / (float)NB) *
                           ((oc == 0) ? 0.70710678118654752f : 1.0f);
        #pragma unroll
        for (int b = 0; b < NB; ++b)
            coef[b] = norm * cosf(PI / (float)NB * ((float)b + 0.5f) * (float)oc);
    }
    // pw is scaled x4 (dropped 0.5 in E/O): log2 shifted by +2; only the c=0
    // DCT row has nonzero coefficient sum (= sqrt(22) before 0.30103 fold)
    const float accInit = (oc == 0) ? (-2.0f * 0.30102999566398120f * sqrtf(22.0f)) : 0.0f;

    // even-sized contiguous frame chunk per wave
    const int chunk = (((NFTOT + nwaves - 1) / nwaves) + 1) & ~1;
    int f0 = gwave * chunk;
    if (f0 >= NFTOT) return;
    int f1 = f0 + chunk; if (f1 > NFTOT) f1 = NFTOT;
    const int f0u = __builtin_amdgcn_readfirstlane(f0);
    const int f1u = __builtin_amdgcn_readfirstlane(f1);

    int bb = f0u / NFR_B;
    int t0 = f0u - bb * NFR_B;
    const float* p0 = x + (size_t)bb * ROWLEN + (size_t)t0 * 128;
    int t1 = t0 + 1;
    const float* p1 = p0 + 128;
    if (t1 == NFR_B) { t1 = 0; p1 += 128; }

    float* ob = out + (size_t)f0u * NB + ((lane < 32) ? oc : (NB + oc));

    float4 v0 = *(const float4*)(p0 + 2 * r);
    float4 v1 = *(const float4*)(p1 + 2 * r);

    for (int f = f0u; f < f1u; f += 2) {
        // next-pair pointers + prefetch
        int nt0 = t1 + 1; const float* np0 = p1 + 128;
        if (nt0 == NFR_B) { nt0 = 0; np0 += 128; }
        int nt1 = nt0 + 1; const float* np1 = np0 + 128;
        if (nt1 == NFR_B) { nt1 = 0; np1 += 128; }
        float4 nv0 = v0, nv1 = v1;
        if (f + 2 < f1u) {
            nv0 = *(const float4*)(np0 + 2 * r);
            nv1 = *(const float4*)(np1 + 2 * r);
        }

        // window + pack (frame0 in .x, frame1 in .y)
        f2 ar2 = { v0.x * winv[0], v1.x * winv[0] };
        f2 ai2 = { v0.y * winv[1], v1.y * winv[1] };
        f2 br2 = { v0.z * winv[2], v1.z * winv[2] };
        f2 bi2 = { v0.w * winv[3], v1.w * winv[3] };

        // stage 0: w = 1 -> res = sgn*x + e
        {
            const f2 e_ar = ex0v(ar2), e_ai = ex0v(ai2);
            const f2 e_br = ex0v(br2), e_bi = ex0v(bi2);
            ar2 = sgn2 * ar2 + e_ar;  ai2 = sgn2 * ai2 + e_ai;
            br2 = sgn2 * br2 + e_br;  bi2 = sgn2 * bi2 + e_bi;
        }
        PSTAGE(1, ex1v)
        PSTAGE(2, ex2v)
        PSTAGE(3, ex3v)
        PSTAGE(4, ex4v)
        PSTAGE(5, ex5v)

        // span-64 stage (lane-local)
        {
            const f2 tr2 = w6r2 * br2 - w6i2 * bi2;
            const f2 ti2 = w6r2 * bi2 + w6i2 * br2;
            const f2 nar = ar2 + tr2, nai = ai2 + ti2;
            br2 = ar2 - tr2; bi2 = ai2 - ti2;
            ar2 = nar; ai2 = nai;
        }

        // Hermitian unpack (0.5 factors dropped -> pw scaled x4)
        const int pidx = (64 - lane) & 63;
        const f2 par2 = shflv(ar2, pidx), pai2 = shflv(ai2, pidx);
        const f2 pbr2 = shflv(br2, pidx), pbi2 = shflv(bi2, pidx);
        const f2 P1r = (lane == 0) ? par2 : pbr2, P1i = (lane == 0) ? pai2 : pbi2;
        const f2 P2r = (lane == 0) ? pbr2 : par2, P2i = (lane == 0) ? pbi2 : pai2;

        f2 Er = ar2 + P1r, Ei = ai2 - P1i;
        f2 Or_ = ar2 - P1r, Oi = ai2 + P1i;
        const f2 X1r = Er + c1_2 * Oi - s1_2 * Or_;
        const f2 X1i = Ei - c1_2 * Or_ - s1_2 * Oi;
        const f2 pw1 = X1r * X1r + X1i * X1i;

        Er = br2 + P2r; Ei = bi2 - P2i;
        Or_ = br2 - P2r; Oi = bi2 + P2i;
        const f2 X2r = Er - s1_2 * Oi - c1_2 * Or_;
        const f2 X2i = Ei + s1_2 * Or_ - c1_2 * Oi;
        const f2 pw2 = X2r * X2r + X2i * X2i;

        // segmented band reduction
        f2 S1 = pw1, T1 = a1_2 * pw1;
        S1 = S1 + ex0v(S1); T1 = T1 + ex0v(T1);
        S1 = S1 + ex1v(S1); T1 = T1 + ex1v(T1);
        S1 = m8_2 * ex2v(S1) + S1; T1 = m8_2 * ex2v(T1) + T1;
        const f2 D1 = S1 - T1;
        f2 S2 = pw2, T2 = a2_2 * pw2;
        S2 = S2 + ex0v(S2); T2 = T2 + ex0v(T2);
        S2 = S2 + ex1v(S2); T2 = T2 + ex1v(T2);
        S2 = S2 + ex2v(S2); T2 = T2 + ex2v(T2);
        S2 = m16_2 * ex3v(S2) + S2; T2 = m16_2 * ex3v(T2) + T2;
        const f2 D2 = S2 - T2;

        // per-band assembly: band c = A(seg c-1) + D(seg c); edges x2
        const f2 gA1 = shflv(T1, idxA), gA2 = shflv(T2, idxA);
        const f2 gD1 = shflv(D1, idxD), gD2 = shflv(D2, idxD);
        const f2 A_prev = selA1 ? gA1 : gA2;
        const f2 D_cur  = selD1 ? gD1 : gD2;
        f2 band = A_prev + D_cur;
        if (c == 0)  band = D_cur + D_cur;
        if (c == 21) band = A_prev + A_prev;

        f2 l2;
        l2.x = __log2f(band.x);
        l2.y = __log2f(band.y);

        // lanes 0..31 serve frame0's bands, 32..63 frame1's
        const float hi_sh = __shfl_xor(l2.y, 32, 64);
        const float Z = (lane < 32) ? l2.x : hi_sh;

        float acc = accInit;
        #pragma unroll
        for (int b = 0; b < NB; ++b) {
            const float zb = __shfl(Z, b, 32);
            acc = fmaf(coef[b], zb, acc);
        }
        if (oc < NB) *ob = acc;

        // advance
        v0 = nv0; v1 = nv1;
        t0 = nt0; t1 = nt1; p0 = np0; p1 = np1;
        ob += 2 * NB;
    }
}

extern "C" void kernel_launch(void* const* d_in, const int* in_sizes, int n_in,
                              void* d_out, int out_size, void* d_ws, size_t ws_size,
                              hipStream_t stream) {
    const float* x = (const float*)d_in[0];
    float* out = (float*)d_out;
    feat_kernel<<<2048, 256, 0, stream>>>(x, out);
}